// Round 3
// baseline (8125.167 us; speedup 1.0000x reference)
//
#include <hip/hip_runtime.h>

typedef unsigned short u16;
typedef unsigned int u32;

typedef __bf16 bf16x8 __attribute__((ext_vector_type(8)));
typedef float  f32x4  __attribute__((ext_vector_type(4)));
typedef short  s16x4  __attribute__((ext_vector_type(4)));

#define N_EMBD 384
#define TT     291
#define NB     128

__device__ __forceinline__ u16 f2bf(float x) {
    union { float f; u32 u; } v; v.f = x;
    u32 r = v.u + 0x7FFFu + ((v.u >> 16) & 1u);
    return (u16)(r >> 16);
}
__device__ __forceinline__ float bfl(u32 u) { return __uint_as_float(u << 16); }
__device__ __forceinline__ float bfh(u32 u) { return __uint_as_float(u & 0xFFFF0000u); }

__device__ __forceinline__ float gelu_f(float x) {
    float u = 0.7978845608028654f * x * (1.f + 0.044715f * x * x);
    float e = __expf(2.f * u);
    float t = 1.f - 2.f / (e + 1.f);   // tanh(u), safe at +-inf
    return 0.5f * x * (1.f + t);
}

// K=16 bf16 MFMA (PV step): A/B are 4 bf16 (2 VGPRs), C/D 4 f32.
__device__ __forceinline__ f32x4 mfma16(s16x4 a, s16x4 b, f32x4 c) {
#if __has_builtin(__builtin_amdgcn_mfma_f32_16x16x16bf16_1k)
    return __builtin_amdgcn_mfma_f32_16x16x16bf16_1k(a, b, c, 0, 0, 0);
#elif __has_builtin(__builtin_amdgcn_mfma_f32_16x16x16_bf16)
    typedef __bf16 bf16x4v __attribute__((ext_vector_type(4)));
    return __builtin_amdgcn_mfma_f32_16x16x16_bf16(__builtin_bit_cast(bf16x4v, a),
                                                   __builtin_bit_cast(bf16x4v, b), c, 0, 0, 0);
#else
    f32x4 d = c;
    asm("v_mfma_f32_16x16x16_bf16 %0, %1, %2, %0" : "+v"(d) : "v"(a), "v"(b));
    return d;
#endif
}

// async global->LDS DMA, 16B per lane. LDS dest must be wave-uniform base +
// lane*16 in lane order (m104/m108) — caller guarantees the mapping.
__device__ __forceinline__ void load16_lds(const u16* g, u16* l) {
    __builtin_amdgcn_global_load_lds(
        (const __attribute__((address_space(1))) u32*)g,
        (__attribute__((address_space(3))) u32*)l, 16, 0, 0);
}

// ---------------------------------------------------------------------------
// 32x32 transpose+convert tile body: out[c0+rr][r0+cc] = in[r0+cc][c0+rr]
// ---------------------------------------------------------------------------
__device__ __forceinline__ void tr_tile(const float* __restrict__ src,
                                        u16* __restrict__ dst,
                                        int R, int C, int r0, int c0, int tid) {
    __shared__ float tile[32][33];
    int cc = tid & 31, rr0 = tid >> 5;
#pragma unroll
    for (int s = 0; s < 4; ++s) {
        int rr = rr0 + s * 8;
        tile[rr][cc] = src[(size_t)(r0 + rr) * C + c0 + cc];
    }
    __syncthreads();
#pragma unroll
    for (int s = 0; s < 4; ++s) {
        int rr = rr0 + s * 8;
        dst[(size_t)(c0 + rr) * R + (r0 + cc)] = f2bf(tile[cc][rr]);
    }
}

// generic: in[R][C] f32 -> out[C][R] bf16, grid (C/32, R/32)
__global__ __launch_bounds__(256) void transpose_cvt(const float* __restrict__ in,
                                                     u16* __restrict__ out, int R, int C) {
    tr_tile(in, out, R, C, blockIdx.y * 32, blockIdx.x * 32, threadIdx.x);
}

// fused per-layer weight transpose: all 4 matrices of layer l, grid 1728
__global__ __launch_bounds__(256) void transpose_layer(const float* __restrict__ attn_w,
                                                       const float* __restrict__ proj_w,
                                                       const float* __restrict__ fc_w,
                                                       const float* __restrict__ fc2_w,
                                                       u16* __restrict__ wqkv,
                                                       u16* __restrict__ wproj,
                                                       u16* __restrict__ wfc,
                                                       u16* __restrict__ wfc2t,
                                                       int l) {
    int t = blockIdx.x;
    const float* src; u16* dst; int R, C, tx, ty;
    if (t < 432)       { int i = t;        src = attn_w + (size_t)l * 384 * 1152; dst = wqkv;  R = 384;  C = 1152; tx = i % 36; ty = i / 36; }
    else if (t < 576)  { int i = t - 432;  src = proj_w + (size_t)l * 384 * 384;  dst = wproj; R = 384;  C = 384;  tx = i % 12; ty = i / 12; }
    else if (t < 1152) { int i = t - 576;  src = fc_w   + (size_t)l * 384 * 1536; dst = wfc;   R = 384;  C = 1536; tx = i % 48; ty = i / 48; }
    else               { int i = t - 1152; src = fc2_w  + (size_t)l * 1536 * 384; dst = wfc2t; R = 1536; C = 384;  tx = i % 12; ty = i / 12; }
    tr_tile(src, dst, R, C, ty * 32, tx * 32, threadIdx.x);
}

// ---------------------------------------------------------------------------
// bf16 MFMA GEMM:  C[M,N] = A[M,K] @ B[K,N]
// A row-major bf16 (row stride K), BT row-major bf16 [N][ldb] (B^T slice).
// Tile 128x128, BK=64, 256 threads (4 waves = 2x2 of 64x64, each 4x4 MFMA).
// LDS: unpadded [128][64] via global_load_lds, 3-bit XOR col-group swizzle.
// XCD-chunked bijective blockIdx swizzle (T1/m204) for A-panel L2 locality.
// K must be a multiple of 64.
// MODE 0: out bf16 = acc+bias        MODE 1: out bf16 = gelu(acc+bias)
// MODE 2: out f32  = resid+acc+bias  MODE 3: out f32  = acc+bias
// out row stride = N. grid (N/128, ceil(M/128))
// ---------------------------------------------------------------------------
template<int MODE>
__global__ __launch_bounds__(256) void gemm_bt(const u16* __restrict__ A,
                                               const u16* __restrict__ BT, int ldb,
                                               const float* __restrict__ bias,
                                               void* __restrict__ out,
                                               const float* __restrict__ resid,
                                               int N, int K) {
    __shared__ u16 As[128 * 64];   // 16 KB
    __shared__ u16 Bs[128 * 64];   // 16 KB
    int tid = threadIdx.x;
    int lane = tid & 63, wave = tid >> 6;
    int wr = wave >> 1, wc = wave & 1;

    // ---- XCD-chunked bijective block swizzle (m204) ----
    int nwg  = gridDim.x * gridDim.y;
    int orig = blockIdx.y * gridDim.x + blockIdx.x;
    int qq = nwg >> 3, rr = nwg & 7;
    int xcd = orig & 7, idx0 = orig >> 3;
    int wg = (xcd < rr ? xcd * (qq + 1) : rr * (qq + 1) + (xcd - rr) * qq) + idx0;
    int bx = wg % gridDim.x, by = wg / gridDim.x;

    const u16* Ab = A  + (size_t)by * 128 * K;
    const u16* Bb = BT + (size_t)bx * 128 * ldb;

    f32x4 acc[4][4];
#pragma unroll
    for (int i = 0; i < 4; ++i)
#pragma unroll
        for (int j = 0; j < 4; ++j)
#pragma unroll
            for (int r = 0; r < 4; ++r) acc[i][j][r] = 0.f;

    int r16  = lane & 15;
    int quad = lane >> 4;
    int sw   = r16 & 7;

    // staging map: seg in [0,1024), 16B each; row = seg>>3, LDS slot cg = seg&7
    // holds global col-group (seg&7) ^ (row&7).
    int srow[4], scol[4];
#pragma unroll
    for (int s = 0; s < 4; ++s) {
        int seg = s * 256 + tid;
        srow[s] = seg >> 3;
        scol[s] = (((seg & 7) ^ (srow[s] & 7)) << 3);
    }

    for (int kt = 0; kt < K; kt += 64) {
#pragma unroll
        for (int s = 0; s < 4; ++s) {
            int seg = s * 256 + tid;
            load16_lds(Ab + (size_t)srow[s] * K   + kt + scol[s], &As[seg * 8]);
            load16_lds(Bb + (size_t)srow[s] * ldb + kt + scol[s], &Bs[seg * 8]);
        }
        __syncthreads();
#pragma unroll
        for (int kk = 0; kk < 2; ++kk) {     // k-offsets 0, 32 within the 64-slice
            bf16x8 af[4], bff[4];
#pragma unroll
            for (int i = 0; i < 4; ++i) {
                int cg = ((kk * 4 + quad) ^ sw) << 3;
                af[i]  = *(const bf16x8*)&As[(wr * 64 + i * 16 + r16) * 64 + cg];
                bff[i] = *(const bf16x8*)&Bs[(wc * 64 + i * 16 + r16) * 64 + cg];
            }
#pragma unroll
            for (int i = 0; i < 4; ++i)
#pragma unroll
                for (int j = 0; j < 4; ++j)
                    acc[i][j] = __builtin_amdgcn_mfma_f32_16x16x32_bf16(af[i], bff[j], acc[i][j], 0, 0, 0);
        }
        __syncthreads();
    }

    int rbase = (lane >> 4) * 4;
#pragma unroll
    for (int i = 0; i < 4; ++i) {
#pragma unroll
        for (int j = 0; j < 4; ++j) {
            int gr0 = by * 128 + wr * 64 + i * 16 + rbase;
            int gc  = bx * 128 + wc * 64 + j * 16 + (lane & 15);
            float bj = bias ? bias[gc] : 0.f;
#pragma unroll
            for (int r = 0; r < 4; ++r) {
                size_t idx = (size_t)(gr0 + r) * N + gc;
                float v = acc[i][j][r] + bj;
                if (MODE == 0)      ((u16*)out)[idx] = f2bf(v);
                else if (MODE == 1) ((u16*)out)[idx] = f2bf(gelu_f(v));
                else if (MODE == 2) ((float*)out)[idx] = resid[idx] + v;
                else                ((float*)out)[idx] = v;
            }
        }
    }
}

// ---------------------------------------------------------------------------
// LayerNorm: rows of 384 f32 -> 384 (bf16 or f32). block 256 = 4 waves,
// one row per wave. input row = row*inRowMul + inRowAdd, output row = row
// ---------------------------------------------------------------------------
template<bool BF16OUT>
__global__ __launch_bounds__(256) void ln_kernel(const float* __restrict__ x,
                                                 const float* __restrict__ w,
                                                 const float* __restrict__ b,
                                                 void* __restrict__ yout,
                                                 int inRowMul, int inRowAdd, int nRows) {
    int row = blockIdx.x * 4 + (threadIdx.x >> 6);
    if (row >= nRows) return;
    const float* xr = x + ((size_t)row * inRowMul + inRowAdd) * N_EMBD;
    int lane = threadIdx.x & 63;
    float v[6], s = 0.f, s2 = 0.f;
#pragma unroll
    for (int i = 0; i < 6; ++i) {
        v[i] = xr[lane + 64 * i];
        s += v[i]; s2 += v[i] * v[i];
    }
#pragma unroll
    for (int off = 32; off > 0; off >>= 1) {
        s  += __shfl_down(s, off);
        s2 += __shfl_down(s2, off);
    }
    float mean = __shfl(s, 0) * (1.f / 384.f);
    float var  = __shfl(s2, 0) * (1.f / 384.f) - mean * mean;
    float rs = rsqrtf(var + 1e-5f);
#pragma unroll
    for (int i = 0; i < 6; ++i) {
        int c = lane + 64 * i;
        float o = (v[i] - mean) * rs * w[c] + b[c];
        if (BF16OUT) ((u16*)yout)[(size_t)row * N_EMBD + c] = f2bf(o);
        else         ((float*)yout)[(size_t)row * N_EMBD + c] = o;
    }
}

// ---------------------------------------------------------------------------
// MFMA attention, v3 (register-P rework, R9).
// One block (512 thr, 8 waves) per (head, batch).
// qkv bf16 [B*291, 1152] -> o bf16 [B*291, 384].
//
// R8 evidence: v2 at 91,136 B LDS -> still 1 block/CU (18.7% occ), MfmaUtil
// 11.5%, 2.97M bank-conflict cycles (the Ps chunk writes were 4-way aliased).
// v3: SWAPPED QK^T (mfma(K,Q), identical loads) puts scores at
// lane(quad,ln) = S[key=kt*16+quad*4+r][q=q0+ln]. That per-lane layout IS
// the A-fragment of mfma_f32_16x16x16_bf16 (row=ln, k=quad*4+j), so P stays
// entirely in registers: Ps LDS buffer deleted -> 80,896 B -> 2 blocks/CU
// (16 waves/CU). Softmax reduces across quads only (shfl_xor 16,32 = 4
// shuffles vs 32). PV = 19 K=16 MFMAs/nt with 8B V reads (2-way = free).
// l-reduce + 4 linv bpermutes overlap the PV MFMA chain.
// ---------------------------------------------------------------------------
__global__ __launch_bounds__(512, 4) void attn_mfma(const u16* __restrict__ qkv,
                                                    u16* __restrict__ o) {
    __shared__ __align__(16) u16 Ks[304 * 64];      // 38,912 B, swizzled
    __shared__ __align__(16) u16 Vt[64 * 328];      // 41,984 B
    int h = blockIdx.x, b = blockIdx.y;
    int tid = threadIdx.x;
    int lane = tid & 63, wave = tid >> 6;
    int ln = lane & 15, quad = lane >> 4;
    int sw = ln & 7;
    const u16* base = qkv + (size_t)b * TT * 1152;

    // ---- stage K rows 0..290 (+clamped pad rows 291..303) via DMA ----
    // chunk c: LDS group (c&7) holds global col-group (c&7)^(row&7).
    for (int c = tid; c < 304 * 8; c += 512) {
        int row = c >> 3;
        int g   = (c & 7) ^ (row & 7);
        int srow = row < TT ? row : TT - 1;
        load16_lds(base + (size_t)srow * 1152 + 384 + h * 64 + g * 8, &Ks[c * 8]);
    }
    // ---- stage V transposed: Vt[d][key] ----
    for (int s = tid; s < TT * 8; s += 512) {
        int dg = s / TT, k = s - dg * TT;
        uint4 v = *(const uint4*)(base + (size_t)k * 1152 + 768 + h * 64 + dg * 8);
        const u16* pv = (const u16*)&v;
#pragma unroll
        for (int j = 0; j < 8; ++j) Vt[(dg * 8 + j) * 328 + k] = pv[j];
    }
    // zero pad cols 291..327 of Vt (disjoint from staged cols, no race)
    for (int s = tid; s < 64 * 37; s += 512) {
        int d = s / 37, c2 = s - d * 37;
        Vt[d * 328 + TT + c2] = 0;
    }
    __syncthreads();

    // ---- per-wave Q-tiles (19 tiles over 8 waves) ----
    for (int qt = wave; qt < 19; qt += 8) {
        int q0 = qt * 16;
        int qrow = q0 + ln; if (qrow > TT - 1) qrow = TT - 1;
        const u16* qp = base + (size_t)qrow * 1152 + h * 64;
        bf16x8 qf0 = *(const bf16x8*)(qp + quad * 8);
        bf16x8 qf1 = *(const bf16x8*)(qp + 32 + quad * 8);

        f32x4 sc[19];
#pragma unroll
        for (int kt = 0; kt < 19; ++kt) {
            const u16* kr = &Ks[(kt * 16 + ln) * 64];   // (row&7) == sw
            bf16x8 kb0 = *(const bf16x8*)&kr[(quad ^ sw) << 3];
            bf16x8 kb1 = *(const bf16x8*)&kr[((4 | quad) ^ sw) << 3];
            f32x4 z = {0.f, 0.f, 0.f, 0.f};
            z = __builtin_amdgcn_mfma_f32_16x16x32_bf16(kb0, qf0, z, 0, 0, 0);   // swapped
            sc[kt] = __builtin_amdgcn_mfma_f32_16x16x32_bf16(kb1, qf1, z, 0, 0, 0);
        }
        // lane holds S[key = kt*16+quad*4+r][q = q0+ln] (raw, unscaled)

        const float C = 0.18033688011112042f;   // 0.125 * log2(e)
        int q = q0 + ln;
        float m = -1e30f;
        if (qt == 18) {
            // tile block containing the readout row (q==290 attends only itself)
#pragma unroll
            for (int kt = 0; kt < 19; ++kt)
#pragma unroll
                for (int r = 0; r < 4; ++r) {
                    int key = kt * 16 + quad * 4 + r;
                    bool ok = (key < TT) && (q != TT - 1 || key == TT - 1);
                    float s = ok ? sc[kt][r] : -1e30f;
                    sc[kt][r] = s;
                    m = fmaxf(m, s);
                }
        } else {
#pragma unroll
            for (int kt = 0; kt < 18; ++kt)
#pragma unroll
                for (int r = 0; r < 4; ++r) m = fmaxf(m, sc[kt][r]);
#pragma unroll
            for (int r = 0; r < 4; ++r) {       // kt=18 spans keys 288..303
                int key = 288 + quad * 4 + r;
                float s = (key < TT) ? sc[18][r] : -1e30f;
                sc[18][r] = s;
                m = fmaxf(m, s);
            }
        }
        m = fmaxf(m, __shfl_xor(m, 16));
        m = fmaxf(m, __shfl_xor(m, 32));

        // exp + pack into K=16 A-fragments (unnormalized); l-sum alongside
        float mc = m * C;
        float l = 0.f;
        s16x4 pa[19];
#pragma unroll
        for (int kt = 0; kt < 19; ++kt)
#pragma unroll
            for (int r = 0; r < 4; ++r) {
                float p = __builtin_amdgcn_exp2f(fmaf(sc[kt][r], C, -mc));
                l += p;
                pa[kt][r] = (short)f2bf(p);
            }
        l += __shfl_xor(l, 16);
        l += __shfl_xor(l, 32);
        float linv = 1.f / l;
        // linv for OUTPUT rows q0+quad*4+r lives at lane quad*4+r (bpermute;
        // overlaps the PV MFMA chain below)
        float linvq[4];
#pragma unroll
        for (int r = 0; r < 4; ++r) linvq[r] = __shfl(linv, quad * 4 + r);

        f32x4 of[4];
#pragma unroll
        for (int nt = 0; nt < 4; ++nt)
#pragma unroll
            for (int r = 0; r < 4; ++r) of[nt][r] = 0.f;
#pragma unroll
        for (int kt = 0; kt < 19; ++kt) {
#pragma unroll
            for (int nt = 0; nt < 4; ++nt) {
                s16x4 vb = *(const s16x4*)&Vt[(nt * 16 + ln) * 328 + kt * 16 + quad * 4];
                of[nt] = mfma16(pa[kt], vb, of[nt]);
            }
        }

#pragma unroll
        for (int nt = 0; nt < 4; ++nt)
#pragma unroll
            for (int r = 0; r < 4; ++r) {
                int qo = q0 + quad * 4 + r;
                if (qo < TT)
                    o[((size_t)(b * TT + qo)) * N_EMBD + h * 64 + nt * 16 + ln] =
                        f2bf(of[nt][r] * linvq[r]);
            }
    }
}

// ---------------------------------------------------------------------------
// Tokenizer helpers
// ---------------------------------------------------------------------------
__global__ __launch_bounds__(256) void patchify_kernel(const float* __restrict__ images,
                                                       u16* __restrict__ P) {
    int idx = blockIdx.x * 256 + threadIdx.x;  // 36864*192 exact
    int col = idx % 192, row = idx / 192;
    int p = row % 144, bt = row / 144;
    int c = col % 3, pp = col / 3;
    int pw = pp & 7, ph = pp >> 3;
    int hp = p / 12, wp = p % 12;
    float v = images[(((size_t)bt * 3 + c) * 96 + hp * 8 + ph) * 96 + wp * 8 + pw];
    P[idx] = f2bf(v);
}

__global__ __launch_bounds__(256) void img_scatter_kernel(const float* __restrict__ imgtok,
                                                          const float* __restrict__ temb,
                                                          const float* __restrict__ pos,
                                                          float* __restrict__ xw) {
    int idx = blockIdx.x * 256 + threadIdx.x;  // 36864*384 exact
    int n = idx % 384, row = idx / 384;
    int p = row % 144, bt = row / 144;
    int t = bt & 1, b = bt >> 1;
    int tok = t * 145 + 1 + p;
    xw[((size_t)b * TT + tok) * N_EMBD + n] =
        imgtok[idx] + temb[t * N_EMBD + n] + pos[(size_t)tok * N_EMBD + n];
}

__global__ __launch_bounds__(384) void st_kernel(const float* __restrict__ state,
                                                 const float* __restrict__ w1,
                                                 const float* __restrict__ b1,
                                                 const float* __restrict__ w2,
                                                 const float* __restrict__ b2,
                                                 const float* __restrict__ temb,
                                                 const float* __restrict__ pos,
                                                 float* __restrict__ xw) {
    int bt = blockIdx.x;
    int t = bt & 1, b = bt >> 1;
    int n = threadIdx.x;
    float s0 = state[bt * 2], s1 = state[bt * 2 + 1];
    float acc = b2[n];
#pragma unroll
    for (int j = 0; j < 32; ++j) {
        float hh = fmaxf(s0 * w1[j] + s1 * w1[32 + j] + b1[j], 0.f);
        acc += hh * w2[j * N_EMBD + n];
    }
    int tok = t * 145;
    xw[((size_t)b * TT + tok) * N_EMBD + n] =
        acc + temb[t * N_EMBD + n] + pos[(size_t)tok * N_EMBD + n];
}

__global__ __launch_bounds__(256) void ro_kernel(const float* __restrict__ readout,
                                                 const float* __restrict__ pos,
                                                 float* __restrict__ xw) {
    int idx = blockIdx.x * 256 + threadIdx.x;  // 128*384 exact
    int n = idx % 384, b = idx / 384;
    xw[((size_t)b * TT + 290) * N_EMBD + n] = readout[n] + pos[(size_t)290 * N_EMBD + n];
}

// ---------------------------------------------------------------------------
// Workspace layout (all offsets 256B-aligned). TOTAL = 175,325,184 B (~167 MB)
// ---------------------------------------------------------------------------
extern "C" void kernel_launch(void* const* d_in, const int* in_sizes, int n_in,
                              void* d_out, int out_size, void* d_ws, size_t ws_size,
                              hipStream_t stream) {
    const float* images   = (const float*)d_in[0];
    const float* state    = (const float*)d_in[1];
    const float* img_w    = (const float*)d_in[2];
    const float* img_b    = (const float*)d_in[3];
    const float* img_temb = (const float*)d_in[4];
    const float* st_w1    = (const float*)d_in[5];
    const float* st_b1    = (const float*)d_in[6];
    const float* st_w2    = (const float*)d_in[7];
    const float* st_b2    = (const float*)d_in[8];
    const float* st_temb  = (const float*)d_in[9];
    const float* readout  = (const float*)d_in[10];
    const float* pos      = (const float*)d_in[11];
    const float* ln1_w    = (const float*)d_in[12];
    const float* ln1_b    = (const float*)d_in[13];
    const float* attn_w   = (const float*)d_in[14];
    const float* attn_b   = (const float*)d_in[15];
    const float* proj_w   = (const float*)d_in[16];
    const float* proj_b   = (const float*)d_in[17];
    const float* ln2_w    = (const float*)d_in[18];
    const float* ln2_b    = (const float*)d_in[19];
    const float* fc_w     = (const float*)d_in[20];
    const float* fc_b     = (const float*)d_in[21];
    const float* fc2_w    = (const float*)d_in[22];
    const float* fc2_b    = (const float*)d_in[23];
    const float* lnf_w    = (const float*)d_in[24];
    const float* lnf_b    = (const float*)d_in[25];

    char* ws = (char*)d_ws;
    float* XW   = (float*)(ws);
    u16*   Y    = (u16*)(ws + 57212928ull);       // also O (attn output)
    u16*   SH   = (u16*)(ws + 85819392ull);       // QKV | G | setup
    u16*   QKV  = SH;
    u16*   G    = SH;
    u16*   P    = SH;                              // setup: patches [36864,192]
    float* IMGT = (float*)(ws + 85819392ull + 14155776ull);  // setup: [36864,384] f32
    u16*   WQKVl  = (u16*)(ws + 171638784ull);    // [1152][384]
    u16*   WPROJl = (u16*)(ws + 172523520ull);    // [384][384]
    u16*   WFCl   = (u16*)(ws + 172818432ull);    // [1536][384]
    u16*   WFC2Tl = (u16*)(ws + 173998080ull);    // [384][1536]
    u16*   WIMG   = (u16*)(ws + 175177728ull);    // [384][192]

    // ---- tokenizers -> XW [128*291, 384] f32 ----
    transpose_cvt<<<dim3(12, 6), 256, 0, stream>>>(img_w, WIMG, 192, 384);
    patchify_kernel<<<27648, 256, 0, stream>>>(images, P);
    gemm_bt<3><<<dim3(3, 288), 256, 0, stream>>>(P, WIMG, 192, img_b, IMGT, nullptr, 384, 192);
    img_scatter_kernel<<<55296, 256, 0, stream>>>(IMGT, img_temb, pos, XW);
    st_kernel<<<256, 384, 0, stream>>>(state, st_w1, st_b1, st_w2, st_b2, st_temb, pos, XW);
    ro_kernel<<<192, 256, 0, stream>>>(readout, pos, XW);

    // ---- transformer layers (M = 37248 = 128*291) ----
    // MLP is M-split (146 + 145 row-blocks): full-width G half fits the QKV
    // region and fc2 runs as ONE K=1536 GEMM per half (halves f32 resid traffic).
    const size_t M0 = 18688;   // 146 * 128
    for (int l = 0; l < 12; ++l) {
        transpose_layer<<<1728, 256, 0, stream>>>(attn_w, proj_w, fc_w, fc2_w,
                                                  WQKVl, WPROJl, WFCl, WFC2Tl, l);
        ln_kernel<true><<<9312, 256, 0, stream>>>(XW, ln1_w + l * 384, ln1_b + l * 384, Y, 1, 0, 37248);
        gemm_bt<0><<<dim3(9, 291), 256, 0, stream>>>(Y, WQKVl, 384, attn_b + l * 1152,
                                                     QKV, nullptr, 1152, 384);
        attn_mfma<<<dim3(6, 128), 512, 0, stream>>>(QKV, Y);   // O aliases Y
        gemm_bt<2><<<dim3(3, 291), 256, 0, stream>>>(Y, WPROJl, 384, proj_b + l * 384,
                                                     XW, XW, 384, 384);
        ln_kernel<true><<<9312, 256, 0, stream>>>(XW, ln2_w + l * 384, ln2_b + l * 384, Y, 1, 0, 37248);
        // MLP half 0: rows [0, 18688)
        gemm_bt<1><<<dim3(12, 146), 256, 0, stream>>>(Y, WFCl, 384, fc_b + l * 1536,
                                                      G, nullptr, 1536, 384);
        gemm_bt<2><<<dim3(3, 146), 256, 0, stream>>>(G, WFC2Tl, 1536, fc2_b + l * 384,
                                                     XW, XW, 384, 1536);
        // MLP half 1: rows [18688, 37248)
        gemm_bt<1><<<dim3(12, 145), 256, 0, stream>>>(Y + M0 * 384, WFCl, 384, fc_b + l * 1536,
                                                      G, nullptr, 1536, 384);
        gemm_bt<2><<<dim3(3, 145), 256, 0, stream>>>(G, WFC2Tl, 1536, fc2_b + l * 384,
                                                     XW + M0 * 384, XW + M0 * 384, 384, 1536);
    }
    // final LN on readout rows -> d_out [128, 384] f32
    ln_kernel<false><<<32, 256, 0, stream>>>(XW, lnf_w, lnf_b, d_out, TT, 290, 128);
}

// Round 5
// 5822.822 us; speedup vs baseline: 1.3954x; 1.3954x over previous
//
#include <hip/hip_runtime.h>

typedef unsigned short u16;
typedef unsigned int u32;

typedef __bf16 bf16x8 __attribute__((ext_vector_type(8)));
typedef float  f32x4  __attribute__((ext_vector_type(4)));
typedef short  s16x4  __attribute__((ext_vector_type(4)));

#define N_EMBD 384
#define TT     291
#define NB     128

__device__ __forceinline__ u16 f2bf(float x) {
    union { float f; u32 u; } v; v.f = x;
    u32 r = v.u + 0x7FFFu + ((v.u >> 16) & 1u);
    return (u16)(r >> 16);
}
__device__ __forceinline__ float bfl(u32 u) { return __uint_as_float(u << 16); }
__device__ __forceinline__ float bfh(u32 u) { return __uint_as_float(u & 0xFFFF0000u); }

__device__ __forceinline__ float gelu_f(float x) {
    float u = 0.7978845608028654f * x * (1.f + 0.044715f * x * x);
    float e = __expf(2.f * u);
    float t = 1.f - 2.f / (e + 1.f);   // tanh(u), safe at +-inf
    return 0.5f * x * (1.f + t);
}

// K=16 bf16 MFMA (PV step): A/B are 4 bf16 (2 VGPRs), C/D 4 f32.
__device__ __forceinline__ f32x4 mfma16(s16x4 a, s16x4 b, f32x4 c) {
#if __has_builtin(__builtin_amdgcn_mfma_f32_16x16x16bf16_1k)
    return __builtin_amdgcn_mfma_f32_16x16x16bf16_1k(a, b, c, 0, 0, 0);
#elif __has_builtin(__builtin_amdgcn_mfma_f32_16x16x16_bf16)
    typedef __bf16 bf16x4v __attribute__((ext_vector_type(4)));
    return __builtin_amdgcn_mfma_f32_16x16x16_bf16(__builtin_bit_cast(bf16x4v, a),
                                                   __builtin_bit_cast(bf16x4v, b), c, 0, 0, 0);
#else
    f32x4 d = c;
    asm("v_mfma_f32_16x16x16_bf16 %0, %1, %2, %0" : "+v"(d) : "v"(a), "v"(b));
    return d;
#endif
}

// async global->LDS DMA, 16B per lane. LDS dest must be wave-uniform base +
// lane*16 in lane order (m104/m108) — caller guarantees the mapping.
__device__ __forceinline__ void load16_lds(const u16* g, u16* l) {
    __builtin_amdgcn_global_load_lds(
        (const __attribute__((address_space(1))) u32*)g,
        (__attribute__((address_space(3))) u32*)l, 16, 0, 0);
}

// ---------------------------------------------------------------------------
// 32x32 transpose+convert tile body: out[c0+rr][r0+cc] = in[r0+cc][c0+rr]
// ---------------------------------------------------------------------------
__device__ __forceinline__ void tr_tile(const float* __restrict__ src,
                                        u16* __restrict__ dst,
                                        int R, int C, int r0, int c0, int tid) {
    __shared__ float tile[32][33];
    int cc = tid & 31, rr0 = tid >> 5;
#pragma unroll
    for (int s = 0; s < 4; ++s) {
        int rr = rr0 + s * 8;
        tile[rr][cc] = src[(size_t)(r0 + rr) * C + c0 + cc];
    }
    __syncthreads();
#pragma unroll
    for (int s = 0; s < 4; ++s) {
        int rr = rr0 + s * 8;
        dst[(size_t)(c0 + rr) * R + (r0 + cc)] = f2bf(tile[cc][rr]);
    }
}

// generic: in[R][C] f32 -> out[C][R] bf16, grid (C/32, R/32)
__global__ __launch_bounds__(256) void transpose_cvt(const float* __restrict__ in,
                                                     u16* __restrict__ out, int R, int C) {
    tr_tile(in, out, R, C, blockIdx.y * 32, blockIdx.x * 32, threadIdx.x);
}

// fused per-layer weight transpose: all 4 matrices of layer l, grid 1728
__global__ __launch_bounds__(256) void transpose_layer(const float* __restrict__ attn_w,
                                                       const float* __restrict__ proj_w,
                                                       const float* __restrict__ fc_w,
                                                       const float* __restrict__ fc2_w,
                                                       u16* __restrict__ wqkv,
                                                       u16* __restrict__ wproj,
                                                       u16* __restrict__ wfc,
                                                       u16* __restrict__ wfc2t,
                                                       int l) {
    int t = blockIdx.x;
    const float* src; u16* dst; int R, C, tx, ty;
    if (t < 432)       { int i = t;        src = attn_w + (size_t)l * 384 * 1152; dst = wqkv;  R = 384;  C = 1152; tx = i % 36; ty = i / 36; }
    else if (t < 576)  { int i = t - 432;  src = proj_w + (size_t)l * 384 * 384;  dst = wproj; R = 384;  C = 384;  tx = i % 12; ty = i / 12; }
    else if (t < 1152) { int i = t - 576;  src = fc_w   + (size_t)l * 384 * 1536; dst = wfc;   R = 384;  C = 1536; tx = i % 48; ty = i / 48; }
    else               { int i = t - 1152; src = fc2_w  + (size_t)l * 1536 * 384; dst = wfc2t; R = 1536; C = 384;  tx = i % 12; ty = i / 12; }
    tr_tile(src, dst, R, C, ty * 32, tx * 32, threadIdx.x);
}

// ---------------------------------------------------------------------------
// bf16 MFMA GEMM:  C[M,N] = A[M,K] @ B[K,N]
// A row-major bf16 (row stride K), BT row-major bf16 [N][ldb] (B^T slice).
// Tile 128x128, BK=64, 256 threads (4 waves = 2x2 of 64x64, each 4x4 MFMA).
// LDS: unpadded [128][64] via global_load_lds, 3-bit XOR col-group swizzle.
// XCD-chunked bijective blockIdx swizzle (T1/m204) for A-panel L2 locality.
// K must be a multiple of 64.
// MODE 0: out bf16 = acc+bias        MODE 1: out bf16 = gelu(acc+bias)
// MODE 2: out f32  = resid+acc+bias  MODE 3: out f32  = acc+bias
// out row stride = N. grid (N/128, ceil(M/128))
// ---------------------------------------------------------------------------
template<int MODE>
__global__ __launch_bounds__(256) void gemm_bt(const u16* __restrict__ A,
                                               const u16* __restrict__ BT, int ldb,
                                               const float* __restrict__ bias,
                                               void* __restrict__ out,
                                               const float* __restrict__ resid,
                                               int N, int K) {
    __shared__ u16 As[128 * 64];   // 16 KB
    __shared__ u16 Bs[128 * 64];   // 16 KB
    int tid = threadIdx.x;
    int lane = tid & 63, wave = tid >> 6;
    int wr = wave >> 1, wc = wave & 1;

    // ---- XCD-chunked bijective block swizzle (m204) ----
    int nwg  = gridDim.x * gridDim.y;
    int orig = blockIdx.y * gridDim.x + blockIdx.x;
    int qq = nwg >> 3, rr = nwg & 7;
    int xcd = orig & 7, idx0 = orig >> 3;
    int wg = (xcd < rr ? xcd * (qq + 1) : rr * (qq + 1) + (xcd - rr) * qq) + idx0;
    int bx = wg % gridDim.x, by = wg / gridDim.x;

    const u16* Ab = A  + (size_t)by * 128 * K;
    const u16* Bb = BT + (size_t)bx * 128 * ldb;

    f32x4 acc[4][4];
#pragma unroll
    for (int i = 0; i < 4; ++i)
#pragma unroll
        for (int j = 0; j < 4; ++j)
#pragma unroll
            for (int r = 0; r < 4; ++r) acc[i][j][r] = 0.f;

    int r16  = lane & 15;
    int quad = lane >> 4;
    int sw   = r16 & 7;

    // staging map: seg in [0,1024), 16B each; row = seg>>3, LDS slot cg = seg&7
    // holds global col-group (seg&7) ^ (row&7).
    int srow[4], scol[4];
#pragma unroll
    for (int s = 0; s < 4; ++s) {
        int seg = s * 256 + tid;
        srow[s] = seg >> 3;
        scol[s] = (((seg & 7) ^ (srow[s] & 7)) << 3);
    }

    for (int kt = 0; kt < K; kt += 64) {
#pragma unroll
        for (int s = 0; s < 4; ++s) {
            int seg = s * 256 + tid;
            load16_lds(Ab + (size_t)srow[s] * K   + kt + scol[s], &As[seg * 8]);
            load16_lds(Bb + (size_t)srow[s] * ldb + kt + scol[s], &Bs[seg * 8]);
        }
        __syncthreads();
#pragma unroll
        for (int kk = 0; kk < 2; ++kk) {     // k-offsets 0, 32 within the 64-slice
            bf16x8 af[4], bff[4];
#pragma unroll
            for (int i = 0; i < 4; ++i) {
                int cg = ((kk * 4 + quad) ^ sw) << 3;
                af[i]  = *(const bf16x8*)&As[(wr * 64 + i * 16 + r16) * 64 + cg];
                bff[i] = *(const bf16x8*)&Bs[(wc * 64 + i * 16 + r16) * 64 + cg];
            }
#pragma unroll
            for (int i = 0; i < 4; ++i)
#pragma unroll
                for (int j = 0; j < 4; ++j)
                    acc[i][j] = __builtin_amdgcn_mfma_f32_16x16x32_bf16(af[i], bff[j], acc[i][j], 0, 0, 0);
        }
        __syncthreads();
    }

    int rbase = (lane >> 4) * 4;
#pragma unroll
    for (int i = 0; i < 4; ++i) {
#pragma unroll
        for (int j = 0; j < 4; ++j) {
            int gr0 = by * 128 + wr * 64 + i * 16 + rbase;
            int gc  = bx * 128 + wc * 64 + j * 16 + (lane & 15);
            float bj = bias ? bias[gc] : 0.f;
#pragma unroll
            for (int r = 0; r < 4; ++r) {
                size_t idx = (size_t)(gr0 + r) * N + gc;
                float v = acc[i][j][r] + bj;
                if (MODE == 0)      ((u16*)out)[idx] = f2bf(v);
                else if (MODE == 1) ((u16*)out)[idx] = f2bf(gelu_f(v));
                else if (MODE == 2) ((float*)out)[idx] = resid[idx] + v;
                else                ((float*)out)[idx] = v;
            }
        }
    }
}

// ---------------------------------------------------------------------------
// LayerNorm: rows of 384 f32 -> 384 (bf16 or f32). block 256 = 4 waves,
// one row per wave. input row = row*inRowMul + inRowAdd, output row = row
// ---------------------------------------------------------------------------
template<bool BF16OUT>
__global__ __launch_bounds__(256) void ln_kernel(const float* __restrict__ x,
                                                 const float* __restrict__ w,
                                                 const float* __restrict__ b,
                                                 void* __restrict__ yout,
                                                 int inRowMul, int inRowAdd, int nRows) {
    int row = blockIdx.x * 4 + (threadIdx.x >> 6);
    if (row >= nRows) return;
    const float* xr = x + ((size_t)row * inRowMul + inRowAdd) * N_EMBD;
    int lane = threadIdx.x & 63;
    float v[6], s = 0.f, s2 = 0.f;
#pragma unroll
    for (int i = 0; i < 6; ++i) {
        v[i] = xr[lane + 64 * i];
        s += v[i]; s2 += v[i] * v[i];
    }
#pragma unroll
    for (int off = 32; off > 0; off >>= 1) {
        s  += __shfl_down(s, off);
        s2 += __shfl_down(s2, off);
    }
    float mean = __shfl(s, 0) * (1.f / 384.f);
    float var  = __shfl(s2, 0) * (1.f / 384.f) - mean * mean;
    float rs = rsqrtf(var + 1e-5f);
#pragma unroll
    for (int i = 0; i < 6; ++i) {
        int c = lane + 64 * i;
        float o = (v[i] - mean) * rs * w[c] + b[c];
        if (BF16OUT) ((u16*)yout)[(size_t)row * N_EMBD + c] = f2bf(o);
        else         ((float*)yout)[(size_t)row * N_EMBD + c] = o;
    }
}

// ---------------------------------------------------------------------------
// MFMA attention, v4 (register-P, spill-fixed, R10; resubmitted R11 after
// infra failure — no kernel change).
// One block (512 thr, 8 waves) per (head, batch).
// qkv bf16 [B*291, 1152] -> o bf16 [B*291, 384].
//
// R9 post-mortem: v3's __launch_bounds__(512,4) acted as min-BLOCKS/CU=4 ->
// 32 waves/CU -> 64-VGPR cap (VGPR_Count=64) while live state needed ~140
// -> scratch spill (FETCH 556MB, WRITE 466MB, MfmaUtil 3%). The register-P
// algorithm itself passed verification.
// v4: __launch_bounds__(512,2) -> 2 blocks/CU -> 128-VGPR cap; and the
// exp/pack/PV is FUSED per kt (no pa[19] array): peak live ~ sc[19](76) +
// of(16) + misc ~ 110 < 128. Normalization by 1/l applied after the PV loop
// (of accumulates unnormalized P.V; l reduced across quads post-loop).
// LDS 80,896 B (no Ps buffer) -> 2 blocks/CU = 16 waves/CU.
// ---------------------------------------------------------------------------
__global__ __launch_bounds__(512, 2) void attn_mfma(const u16* __restrict__ qkv,
                                                    u16* __restrict__ o) {
    __shared__ __align__(16) u16 Ks[304 * 64];      // 38,912 B, swizzled
    __shared__ __align__(16) u16 Vt[64 * 328];      // 41,984 B
    int h = blockIdx.x, b = blockIdx.y;
    int tid = threadIdx.x;
    int lane = tid & 63, wave = tid >> 6;
    int ln = lane & 15, quad = lane >> 4;
    int sw = ln & 7;
    const u16* base = qkv + (size_t)b * TT * 1152;

    // ---- stage K rows 0..290 (+clamped pad rows 291..303) via DMA ----
    // chunk c: LDS group (c&7) holds global col-group (c&7)^(row&7).
    for (int c = tid; c < 304 * 8; c += 512) {
        int row = c >> 3;
        int g   = (c & 7) ^ (row & 7);
        int srow = row < TT ? row : TT - 1;
        load16_lds(base + (size_t)srow * 1152 + 384 + h * 64 + g * 8, &Ks[c * 8]);
    }
    // ---- stage V transposed: Vt[d][key] ----
    for (int s = tid; s < TT * 8; s += 512) {
        int dg = s / TT, k = s - dg * TT;
        uint4 v = *(const uint4*)(base + (size_t)k * 1152 + 768 + h * 64 + dg * 8);
        const u16* pv = (const u16*)&v;
#pragma unroll
        for (int j = 0; j < 8; ++j) Vt[(dg * 8 + j) * 328 + k] = pv[j];
    }
    // zero pad cols 291..327 of Vt (disjoint from staged cols, no race)
    for (int s = tid; s < 64 * 37; s += 512) {
        int d = s / 37, c2 = s - d * 37;
        Vt[d * 328 + TT + c2] = 0;
    }
    __syncthreads();

    // ---- per-wave Q-tiles (19 tiles over 8 waves) ----
    for (int qt = wave; qt < 19; qt += 8) {
        int q0 = qt * 16;
        int qrow = q0 + ln; if (qrow > TT - 1) qrow = TT - 1;
        const u16* qp = base + (size_t)qrow * 1152 + h * 64;
        bf16x8 qf0 = *(const bf16x8*)(qp + quad * 8);
        bf16x8 qf1 = *(const bf16x8*)(qp + 32 + quad * 8);

        f32x4 sc[19];
#pragma unroll
        for (int kt = 0; kt < 19; ++kt) {
            const u16* kr = &Ks[(kt * 16 + ln) * 64];   // (row&7) == sw
            bf16x8 kb0 = *(const bf16x8*)&kr[(quad ^ sw) << 3];
            bf16x8 kb1 = *(const bf16x8*)&kr[((4 | quad) ^ sw) << 3];
            f32x4 z = {0.f, 0.f, 0.f, 0.f};
            z = __builtin_amdgcn_mfma_f32_16x16x32_bf16(kb0, qf0, z, 0, 0, 0);   // swapped
            sc[kt] = __builtin_amdgcn_mfma_f32_16x16x32_bf16(kb1, qf1, z, 0, 0, 0);
        }
        // lane holds S[key = kt*16+quad*4+r][q = q0+ln] (raw, unscaled)

        const float C = 0.18033688011112042f;   // 0.125 * log2(e)
        int q = q0 + ln;
        float m = -1e30f;
        if (qt == 18) {
            // tile block containing the readout row (q==290 attends only itself)
#pragma unroll
            for (int kt = 0; kt < 19; ++kt)
#pragma unroll
                for (int r = 0; r < 4; ++r) {
                    int key = kt * 16 + quad * 4 + r;
                    bool ok = (key < TT) && (q != TT - 1 || key == TT - 1);
                    float s = ok ? sc[kt][r] : -1e30f;
                    sc[kt][r] = s;
                    m = fmaxf(m, s);
                }
        } else {
#pragma unroll
            for (int kt = 0; kt < 18; ++kt)
#pragma unroll
                for (int r = 0; r < 4; ++r) m = fmaxf(m, sc[kt][r]);
#pragma unroll
            for (int r = 0; r < 4; ++r) {       // kt=18 spans keys 288..303
                int key = 288 + quad * 4 + r;
                float s = (key < TT) ? sc[18][r] : -1e30f;
                sc[18][r] = s;
                m = fmaxf(m, s);
            }
        }
        m = fmaxf(m, __shfl_xor(m, 16));
        m = fmaxf(m, __shfl_xor(m, 32));

        // fused exp + pack + PV per kt (no pa[] array -> no spill):
        // of accumulates UNNORMALIZED P.V; l summed alongside.
        float mc = m * C;
        float l = 0.f;
        f32x4 of[4];
#pragma unroll
        for (int nt = 0; nt < 4; ++nt)
#pragma unroll
            for (int r = 0; r < 4; ++r) of[nt][r] = 0.f;
#pragma unroll
        for (int kt = 0; kt < 19; ++kt) {
            s16x4 pa;
#pragma unroll
            for (int r = 0; r < 4; ++r) {
                float p = __builtin_amdgcn_exp2f(fmaf(sc[kt][r], C, -mc));
                l += p;
                pa[r] = (short)f2bf(p);
            }
#pragma unroll
            for (int nt = 0; nt < 4; ++nt) {
                s16x4 vb = *(const s16x4*)&Vt[(nt * 16 + ln) * 328 + kt * 16 + quad * 4];
                of[nt] = mfma16(pa, vb, of[nt]);
            }
        }
        l += __shfl_xor(l, 16);
        l += __shfl_xor(l, 32);
        float linv = 1.f / l;
        // linv for OUTPUT rows q0+quad*4+r lives at lane quad*4+r
        float linvq[4];
#pragma unroll
        for (int r = 0; r < 4; ++r) linvq[r] = __shfl(linv, quad * 4 + r);

#pragma unroll
        for (int nt = 0; nt < 4; ++nt)
#pragma unroll
            for (int r = 0; r < 4; ++r) {
                int qo = q0 + quad * 4 + r;
                if (qo < TT)
                    o[((size_t)(b * TT + qo)) * N_EMBD + h * 64 + nt * 16 + ln] =
                        f2bf(of[nt][r] * linvq[r]);
            }
    }
}

// ---------------------------------------------------------------------------
// Tokenizer helpers
// ---------------------------------------------------------------------------
__global__ __launch_bounds__(256) void patchify_kernel(const float* __restrict__ images,
                                                       u16* __restrict__ P) {
    int idx = blockIdx.x * 256 + threadIdx.x;  // 36864*192 exact
    int col = idx % 192, row = idx / 192;
    int p = row % 144, bt = row / 144;
    int c = col % 3, pp = col / 3;
    int pw = pp & 7, ph = pp >> 3;
    int hp = p / 12, wp = p % 12;
    float v = images[(((size_t)bt * 3 + c) * 96 + hp * 8 + ph) * 96 + wp * 8 + pw];
    P[idx] = f2bf(v);
}

__global__ __launch_bounds__(256) void img_scatter_kernel(const float* __restrict__ imgtok,
                                                          const float* __restrict__ temb,
                                                          const float* __restrict__ pos,
                                                          float* __restrict__ xw) {
    int idx = blockIdx.x * 256 + threadIdx.x;  // 36864*384 exact
    int n = idx % 384, row = idx / 384;
    int p = row % 144, bt = row / 144;
    int t = bt & 1, b = bt >> 1;
    int tok = t * 145 + 1 + p;
    xw[((size_t)b * TT + tok) * N_EMBD + n] =
        imgtok[idx] + temb[t * N_EMBD + n] + pos[(size_t)tok * N_EMBD + n];
}

__global__ __launch_bounds__(384) void st_kernel(const float* __restrict__ state,
                                                 const float* __restrict__ w1,
                                                 const float* __restrict__ b1,
                                                 const float* __restrict__ w2,
                                                 const float* __restrict__ b2,
                                                 const float* __restrict__ temb,
                                                 const float* __restrict__ pos,
                                                 float* __restrict__ xw) {
    int bt = blockIdx.x;
    int t = bt & 1, b = bt >> 1;
    int n = threadIdx.x;
    float s0 = state[bt * 2], s1 = state[bt * 2 + 1];
    float acc = b2[n];
#pragma unroll
    for (int j = 0; j < 32; ++j) {
        float hh = fmaxf(s0 * w1[j] + s1 * w1[32 + j] + b1[j], 0.f);
        acc += hh * w2[j * N_EMBD + n];
    }
    int tok = t * 145;
    xw[((size_t)b * TT + tok) * N_EMBD + n] =
        acc + temb[t * N_EMBD + n] + pos[(size_t)tok * N_EMBD + n];
}

__global__ __launch_bounds__(256) void ro_kernel(const float* __restrict__ readout,
                                                 const float* __restrict__ pos,
                                                 float* __restrict__ xw) {
    int idx = blockIdx.x * 256 + threadIdx.x;  // 128*384 exact
    int n = idx % 384, b = idx / 384;
    xw[((size_t)b * TT + 290) * N_EMBD + n] = readout[n] + pos[(size_t)290 * N_EMBD + n];
}

// ---------------------------------------------------------------------------
// Workspace layout (all offsets 256B-aligned). TOTAL = 175,325,184 B (~167 MB)
// ---------------------------------------------------------------------------
extern "C" void kernel_launch(void* const* d_in, const int* in_sizes, int n_in,
                              void* d_out, int out_size, void* d_ws, size_t ws_size,
                              hipStream_t stream) {
    const float* images   = (const float*)d_in[0];
    const float* state    = (const float*)d_in[1];
    const float* img_w    = (const float*)d_in[2];
    const float* img_b    = (const float*)d_in[3];
    const float* img_temb = (const float*)d_in[4];
    const float* st_w1    = (const float*)d_in[5];
    const float* st_b1    = (const float*)d_in[6];
    const float* st_w2    = (const float*)d_in[7];
    const float* st_b2    = (const float*)d_in[8];
    const float* st_temb  = (const float*)d_in[9];
    const float* readout  = (const float*)d_in[10];
    const float* pos      = (const float*)d_in[11];
    const float* ln1_w    = (const float*)d_in[12];
    const float* ln1_b    = (const float*)d_in[13];
    const float* attn_w   = (const float*)d_in[14];
    const float* attn_b   = (const float*)d_in[15];
    const float* proj_w   = (const float*)d_in[16];
    const float* proj_b   = (const float*)d_in[17];
    const float* ln2_w    = (const float*)d_in[18];
    const float* ln2_b    = (const float*)d_in[19];
    const float* fc_w     = (const float*)d_in[20];
    const float* fc_b     = (const float*)d_in[21];
    const float* fc2_w    = (const float*)d_in[22];
    const float* fc2_b    = (const float*)d_in[23];
    const float* lnf_w    = (const float*)d_in[24];
    const float* lnf_b    = (const float*)d_in[25];

    char* ws = (char*)d_ws;
    float* XW   = (float*)(ws);
    u16*   Y    = (u16*)(ws + 57212928ull);       // also O (attn output)
    u16*   SH   = (u16*)(ws + 85819392ull);       // QKV | G | setup
    u16*   QKV  = SH;
    u16*   G    = SH;
    u16*   P    = SH;                              // setup: patches [36864,192]
    float* IMGT = (float*)(ws + 85819392ull + 14155776ull);  // setup: [36864,384] f32
    u16*   WQKVl  = (u16*)(ws + 171638784ull);    // [1152][384]
    u16*   WPROJl = (u16*)(ws + 172523520ull);    // [384][384]
    u16*   WFCl   = (u16*)(ws + 172818432ull);    // [1536][384]
    u16*   WFC2Tl = (u16*)(ws + 173998080ull);    // [384][1536]
    u16*   WIMG   = (u16*)(ws + 175177728ull);    // [384][192]

    // ---- tokenizers -> XW [128*291, 384] f32 ----
    transpose_cvt<<<dim3(12, 6), 256, 0, stream>>>(img_w, WIMG, 192, 384);
    patchify_kernel<<<27648, 256, 0, stream>>>(images, P);
    gemm_bt<3><<<dim3(3, 288), 256, 0, stream>>>(P, WIMG, 192, img_b, IMGT, nullptr, 384, 192);
    img_scatter_kernel<<<55296, 256, 0, stream>>>(IMGT, img_temb, pos, XW);
    st_kernel<<<256, 384, 0, stream>>>(state, st_w1, st_b1, st_w2, st_b2, st_temb, pos, XW);
    ro_kernel<<<192, 256, 0, stream>>>(readout, pos, XW);

    // ---- transformer layers (M = 37248 = 128*291) ----
    // MLP is M-split (146 + 145 row-blocks): full-width G half fits the QKV
    // region and fc2 runs as ONE K=1536 GEMM per half (halves f32 resid traffic).
    const size_t M0 = 18688;   // 146 * 128
    for (int l = 0; l < 12; ++l) {
        transpose_layer<<<1728, 256, 0, stream>>>(attn_w, proj_w, fc_w, fc2_w,
                                                  WQKVl, WPROJl, WFCl, WFC2Tl, l);
        ln_kernel<true><<<9312, 256, 0, stream>>>(XW, ln1_w + l * 384, ln1_b + l * 384, Y, 1, 0, 37248);
        gemm_bt<0><<<dim3(9, 291), 256, 0, stream>>>(Y, WQKVl, 384, attn_b + l * 1152,
                                                     QKV, nullptr, 1152, 384);
        attn_mfma<<<dim3(6, 128), 512, 0, stream>>>(QKV, Y);   // O aliases Y
        gemm_bt<2><<<dim3(3, 291), 256, 0, stream>>>(Y, WPROJl, 384, proj_b + l * 384,
                                                     XW, XW, 384, 384);
        ln_kernel<true><<<9312, 256, 0, stream>>>(XW, ln2_w + l * 384, ln2_b + l * 384, Y, 1, 0, 37248);
        // MLP half 0: rows [0, 18688)
        gemm_bt<1><<<dim3(12, 146), 256, 0, stream>>>(Y, WFCl, 384, fc_b + l * 1536,
                                                      G, nullptr, 1536, 384);
        gemm_bt<2><<<dim3(3, 146), 256, 0, stream>>>(G, WFC2Tl, 1536, fc2_b + l * 384,
                                                     XW, XW, 384, 1536);
        // MLP half 1: rows [18688, 37248)
        gemm_bt<1><<<dim3(12, 145), 256, 0, stream>>>(Y + M0 * 384, WFCl, 384, fc_b + l * 1536,
                                                      G, nullptr, 1536, 384);
        gemm_bt<2><<<dim3(3, 145), 256, 0, stream>>>(G, WFC2Tl, 1536, fc2_b + l * 384,
                                                     XW + M0 * 384, XW + M0 * 384, 384, 1536);
    }
    // final LN on readout rows -> d_out [128, 384] f32
    ln_kernel<false><<<32, 256, 0, stream>>>(XW, lnf_w, lnf_b, d_out, TT, 290, 128);
}